// Round 1
// baseline (4874.524 us; speedup 1.0000x reference)
//
#include <hip/hip_runtime.h>

// Problem constants (from reference):
//   x: (64, 3, 512, 512) fp32, w: (16, 3, 3, 3), bias: (16,)
//   conv VALID -> (64,16,510,510); avgpool2x2 -> (64,16,255,255);
//   sigmoid; sum over (C,H,W) -> (64,)
// Rewrite: avgpool(conv3x3 stride1) == conv4x4 stride2 with
//   w_eff[ky][kx] = 0.25 * sum_{py,px in {0,1}} w[ky-py][kx-px] (valid idx)

#define IC 3
#define OCH 16
#define HH 512
#define WW 512
#define HP 255
#define WP 255
#define ROWS 8  // pooled rows per block

typedef float v2f __attribute__((ext_vector_type(2)));

__device__ __forceinline__ float fast_sigmoid(float v) {
    float e = __expf(-v);                      // v_exp_f32 path
    return __builtin_amdgcn_rcpf(1.0f + e);    // v_rcp_f32
}

__global__ __launch_bounds__(256)
void conv_pool_sig_sum(const float* __restrict__ x,
                       const float* __restrict__ w,
                       const float* __restrict__ bias,
                       float* __restrict__ out)
{
    // LDS: effective 4x4 stride-2 weights, layout [(ic*4+ky)*16+oc] -> float4 over kx
    __shared__ float4 wl4[IC * 4 * OCH];
    __shared__ float bl[OCH];
    float* wl = (float*)wl4;

    const int tid = threadIdx.x;

    // Build w_eff in LDS (768 scalars, 256 threads -> 3 each)
    for (int i = tid; i < IC * 4 * OCH * 4; i += 256) {
        int kx = i & 3;
        int oc = (i >> 2) & 15;
        int ky = (i >> 6) & 3;
        int ic = i >> 8;
        float s = 0.f;
#pragma unroll
        for (int py = 0; py < 2; ++py) {
            int r = ky - py;
            if (r < 0 || r > 2) continue;
#pragma unroll
            for (int px = 0; px < 2; ++px) {
                int c = kx - px;
                if (c < 0 || c > 2) continue;
                s += w[((oc * IC + ic) * 3 + r) * 3 + c];
            }
        }
        wl[i] = 0.25f * s;
    }
    if (tid < OCH) bl[tid] = bias[tid];
    __syncthreads();

    const int b = blockIdx.y;
    const int hp0 = blockIdx.x * ROWS;
    const int p = tid & 127;       // pooled-column pair index: wp = {2p, 2p+1}
    const int rhalf = tid >> 7;    // which of 2 concurrent pooled rows
    const bool v1 = (p < 127);     // wp1 = 2p+1 valid iff < 255
    const int xcol = 4 * p;        // first input column of the pair's window
    const int tail_off = v1 ? 4 : 0;  // avoid OOB read at the right edge
    const float* xb = x + (size_t)b * IC * HH * WW;

    float lsum = 0.f;

    for (int rr = 0; rr < ROWS / 2; ++rr) {
        int hp = hp0 + 2 * rr + rhalf;
        if (hp >= HP) continue;
        int y0 = 2 * hp;

        v2f acc[OCH];
#pragma unroll
        for (int oc = 0; oc < OCH; ++oc) acc[oc] = (v2f){bl[oc], bl[oc]};

#pragma unroll
        for (int ic = 0; ic < IC; ++ic) {
            const float* xq = xb + ((size_t)ic * HH + y0) * WW + xcol;
#pragma unroll
            for (int ky = 0; ky < 4; ++ky) {
                const float* xr = xq + ky * WW;
                float4 xa = *(const float4*)xr;                  // cols 4p..4p+3 (16B aligned)
                float2 xt = *(const float2*)(xr + tail_off);     // cols 4p+4..4p+5 (masked garbage at edge)
                v2f xp0 = {xa.x, xa.z};
                v2f xp1 = {xa.y, xa.w};
                v2f xp2 = {xa.z, xt.x};
                v2f xp3 = {xa.w, xt.y};
                const float4* wrow = wl4 + (ic * 4 + ky) * OCH;
#pragma unroll
                for (int oc = 0; oc < OCH; ++oc) {
                    float4 wv = wrow[oc];    // broadcast ds_read_b128 (conflict-free)
                    acc[oc] += xp0 * wv.x;
                    acc[oc] += xp1 * wv.y;
                    acc[oc] += xp2 * wv.z;
                    acc[oc] += xp3 * wv.w;
                }
            }
        }

#pragma unroll
        for (int oc = 0; oc < OCH; ++oc) {
            lsum += fast_sigmoid(acc[oc].x);
            float s1 = fast_sigmoid(acc[oc].y);
            lsum += v1 ? s1 : 0.f;
        }
    }

    // wave64 butterfly reduction, one atomic per wave
#pragma unroll
    for (int off = 32; off > 0; off >>= 1)
        lsum += __shfl_xor(lsum, off, 64);
    if ((tid & 63) == 0) atomicAdd(out + b, lsum);
}

extern "C" void kernel_launch(void* const* d_in, const int* in_sizes, int n_in,
                              void* d_out, int out_size, void* d_ws, size_t ws_size,
                              hipStream_t stream) {
    const float* x = (const float*)d_in[0];
    const float* w = (const float*)d_in[1];
    const float* bias = (const float*)d_in[2];
    float* out = (float*)d_out;

    // d_out is re-poisoned before every timed launch -> zero it (graph-capture safe)
    hipMemsetAsync(out, 0, out_size * sizeof(float), stream);

    dim3 grid((HP + ROWS - 1) / ROWS, 64);  // 32 x 64 = 2048 blocks
    dim3 block(256);
    conv_pool_sig_sum<<<grid, block, 0, stream>>>(x, w, bias, out);
}

// Round 2
// 681.340 us; speedup vs baseline: 7.1543x; 7.1543x over previous
//
#include <hip/hip_runtime.h>

// x: (64,3,512,512) fp32 -> conv3x3 VALID + avgpool2x2 + sigmoid + per-batch sum.
// Fused as stride-2 4x4 conv: w_eff[ky][kx] = 0.25*sum_{py,px in {0,1}} w[ky-py][kx-px].
// Thread = (oc, pooled-col-pair): 48 w_eff floats live in REGISTERS (round-0 spill fix:
// keeping all 16 oc per thread needed 768 weight regs -> scratch thrash, 2.4 GB writes).

#define IC 3
#define OCH 16
#define HH 512
#define WW 512
#define HP 255
#define STRIPS 5
#define SROWS 51  // 255 = 5 * 51

__device__ __forceinline__ float fast_sigmoid(float v) {
    float e = __expf(-v);                    // v_exp_f32 path
    return __builtin_amdgcn_rcpf(1.0f + e);  // v_rcp_f32
}

__global__ __launch_bounds__(256, 4)
void conv_pool_sig_sum(const float* __restrict__ x,
                       const float* __restrict__ w,
                       const float* __restrict__ bias,
                       float* __restrict__ out)
{
    const int tid = threadIdx.x;
    const int oc = tid & 15;                    // 16 output channels across lanes
    const int lpair = tid >> 4;                 // 16 column-pairs per block
    const int gpair = blockIdx.x * 16 + lpair;  // 0..127; pooled cols {2g, 2g+1}
    const bool v1 = (gpair < 127);              // pooled col 255 doesn't exist
    const int c0 = 4 * gpair;                   // input col base (max 508, 16B aligned)
    const int b = blockIdx.z;
    const int hp0 = blockIdx.y * SROWS;

    // Per-thread w_eff for this oc only: 27 broadcast loads -> 48 registers.
    float wk[IC][3][3];
    const float* wg = w + oc * (IC * 9);
#pragma unroll
    for (int ic = 0; ic < IC; ++ic)
#pragma unroll
        for (int r = 0; r < 3; ++r)
#pragma unroll
            for (int c = 0; c < 3; ++c)
                wk[ic][r][c] = wg[ic * 9 + r * 3 + c];

    float weff[IC][4][4];
#pragma unroll
    for (int ic = 0; ic < IC; ++ic)
#pragma unroll
        for (int ky = 0; ky < 4; ++ky)
#pragma unroll
            for (int kx = 0; kx < 4; ++kx) {
                float s = 0.f;
#pragma unroll
                for (int py = 0; py < 2; ++py) {
                    int r = ky - py;
                    if (r < 0 || r > 2) continue;
#pragma unroll
                    for (int px = 0; px < 2; ++px) {
                        int c = kx - px;
                        if (c < 0 || c > 2) continue;
                        s += wk[ic][r][c];
                    }
                }
                weff[ic][ky][kx] = 0.25f * s;
            }
    const float bv = bias[oc];

    const float* xb = x + ((size_t)b * IC * HH + (size_t)2 * hp0) * WW + c0;
    const int tail = v1 ? 4 : 0;  // right edge: re-read in-bounds, result masked

    float lsum = 0.f, lsum1 = 0.f;
    for (int s = 0; s < SROWS; ++s) {
        float a0 = bv, a1 = bv;
#pragma unroll
        for (int ic = 0; ic < IC; ++ic) {
            const float* pr = xb + (size_t)ic * HH * WW;
#pragma unroll
            for (int r = 0; r < 4; ++r) {
                float4 xa = *(const float4*)(pr + r * WW);         // cols c0..c0+3
                float2 xt = *(const float2*)(pr + r * WW + tail);  // cols c0+4..c0+5
                a0 += weff[ic][r][0] * xa.x + weff[ic][r][1] * xa.y
                    + weff[ic][r][2] * xa.z + weff[ic][r][3] * xa.w;
                a1 += weff[ic][r][0] * xa.z + weff[ic][r][1] * xa.w
                    + weff[ic][r][2] * xt.x + weff[ic][r][3] * xt.y;
            }
        }
        lsum += fast_sigmoid(a0);
        lsum1 += fast_sigmoid(a1);
        xb += 2 * WW;
    }
    lsum += v1 ? lsum1 : 0.f;

    // wave64 butterfly, one atomic per wave (4 per block, 64 target addrs)
#pragma unroll
    for (int off = 32; off > 0; off >>= 1)
        lsum += __shfl_xor(lsum, off, 64);
    if ((tid & 63) == 0) atomicAdd(out + b, lsum);
}

extern "C" void kernel_launch(void* const* d_in, const int* in_sizes, int n_in,
                              void* d_out, int out_size, void* d_ws, size_t ws_size,
                              hipStream_t stream) {
    const float* x = (const float*)d_in[0];
    const float* w = (const float*)d_in[1];
    const float* bias = (const float*)d_in[2];
    float* out = (float*)d_out;

    hipMemsetAsync(out, 0, out_size * sizeof(float), stream);

    dim3 grid(8, STRIPS, 64);  // 8 col-groups x 5 row-strips x 64 batches = 2560 blocks
    dim3 block(256);
    conv_pool_sig_sum<<<grid, block, 0, stream>>>(x, w, bias, out);
}

// Round 3
// 335.359 us; speedup vs baseline: 14.5352x; 2.0317x over previous
//
#include <hip/hip_runtime.h>

// x: (64,3,512,512) fp32 -> conv3x3 VALID + avgpool2x2 + sigmoid + per-batch sum.
// Fused stride-2 4x4 conv: w_eff[ky][kx] = 0.25*sum_{py,px in {0,1}} w[ky-py][kx-px].
//
// R2 structure: thread = pooled-col-pair (x loaded ONCE into 72 regs), oc looped
// with wave-uniform weights from a precomputed d_ws table -> s_load (SGPRs),
// killing R1's 16x L1 load duplication (9.6 GB of L1 traffic -> 0.6 GB).

#define IC 3
#define OCH 16
#define HH 512
#define WW 512
#define HP 255
#define SROWS 5
#define STRIPS 51  // 51 * 5 = 255 pooled rows

typedef float v2f __attribute__((ext_vector_type(2)));

__device__ __forceinline__ float fast_sigmoid(float v) {
    float e = __expf(-v);                    // v_exp_f32
    return __builtin_amdgcn_rcpf(1.0f + e);  // v_rcp_f32
}

// d_ws layout: per oc, 64 floats: [48 w_eff, idx = ic*16 + ky*4 + kx][bias][15 pad]
// (256 B stride keeps s_load_dwordx16 64B-aligned)
__global__ void build_weff(const float* __restrict__ w,
                           const float* __restrict__ bias,
                           float* __restrict__ ws)
{
    const int i = threadIdx.x;
    for (int idx = i; idx < OCH * 48; idx += 256) {
        int oc = idx / 48;
        int rem = idx - oc * 48;
        int ic = rem >> 4;
        int ky = (rem >> 2) & 3;
        int kx = rem & 3;
        float s = 0.f;
#pragma unroll
        for (int py = 0; py < 2; ++py) {
            int r = ky - py;
            if (r < 0 || r > 2) continue;
#pragma unroll
            for (int px = 0; px < 2; ++px) {
                int c = kx - px;
                if (c < 0 || c > 2) continue;
                s += w[((oc * IC + ic) * 3 + r) * 3 + c];
            }
        }
        ws[oc * 64 + rem] = 0.25f * s;
    }
    if (i < OCH) ws[i * 64 + 48] = bias[i];
}

__global__ __launch_bounds__(128)
void conv_pool_sig_sum(const float* __restrict__ x,
                       const float* __restrict__ wws,
                       float* __restrict__ out)
{
    const int tid = threadIdx.x;      // 0..127 == pooled-col-pair index
    const bool v1 = (tid < 127);      // pooled col 2*127+1 = 255 doesn't exist
    const int c0 = 4 * tid;           // input col base (max 508)
    const int b = blockIdx.y;
    const int hp0 = blockIdx.x * SROWS;
    const int tail = v1 ? 4 : 0;      // right edge: re-read in-bounds, masked later

    const float* xb = x + ((size_t)b * IC * HH + (size_t)2 * hp0) * WW + c0;

    float lsum = 0.f, lsum1 = 0.f;

    for (int s = 0; s < SROWS; ++s) {
        // Load the 4x6 window for all 3 ic ONCE (72 floats in VGPRs),
        // reused across all 16 output channels.
        float4 xa[IC][4];
        float2 xt[IC][4];
#pragma unroll
        for (int ic = 0; ic < IC; ++ic) {
            const float* pr = xb + (size_t)ic * HH * WW;
#pragma unroll
            for (int r = 0; r < 4; ++r) {
                xa[ic][r] = *(const float4*)(pr + r * WW);         // cols c0..c0+3
                xt[ic][r] = *(const float2*)(pr + r * WW + tail);  // cols c0+4..c0+5
            }
        }

        // oc loop NOT unrolled: only one oc's 49 weights live (s_load, SGPRs).
#pragma unroll 1
        for (int oc = 0; oc < OCH; ++oc) {
            const float* we = wws + oc * 64;   // wave-uniform address -> s_load
            const float bv = we[48];
            v2f acc = {bv, bv};
#pragma unroll
            for (int ic = 0; ic < IC; ++ic) {
#pragma unroll
                for (int r = 0; r < 4; ++r) {
                    const float4 a = xa[ic][r];
                    const float2 t = xt[ic][r];
                    const float* wr = we + ic * 16 + r * 4;
                    acc += (v2f){a.x, a.z} * wr[0];
                    acc += (v2f){a.y, a.w} * wr[1];
                    acc += (v2f){a.z, t.x} * wr[2];
                    acc += (v2f){a.w, t.y} * wr[3];
                }
            }
            lsum  += fast_sigmoid(acc.x);
            lsum1 += fast_sigmoid(acc.y);
        }
        xb += 2 * WW;
    }
    lsum += v1 ? lsum1 : 0.f;

    // wave64 butterfly, one atomic per wave (2 per block)
#pragma unroll
    for (int off = 32; off > 0; off >>= 1)
        lsum += __shfl_xor(lsum, off, 64);
    if ((tid & 63) == 0) atomicAdd(out + b, lsum);
}

extern "C" void kernel_launch(void* const* d_in, const int* in_sizes, int n_in,
                              void* d_out, int out_size, void* d_ws, size_t ws_size,
                              hipStream_t stream) {
    const float* x = (const float*)d_in[0];
    const float* w = (const float*)d_in[1];
    const float* bias = (const float*)d_in[2];
    float* out = (float*)d_out;
    float* wws = (float*)d_ws;  // 16 * 64 floats = 4 KB

    hipMemsetAsync(out, 0, out_size * sizeof(float), stream);
    build_weff<<<1, 256, 0, stream>>>(w, bias, wws);

    dim3 grid(STRIPS, 64);  // 51 row-strips x 64 batches = 3264 blocks
    conv_pool_sig_sum<<<grid, 128, 0, stream>>>(x, wws, out);
}